// Round 1
// baseline (75.506 us; speedup 1.0000x reference)
//
#include <hip/hip_runtime.h>
#include <cstdint>

#define D 128
#define NEXP 9
#define TPB 256

// Pack two fp32 into one uint32 of bf16 (round-to-nearest-even).
__device__ __forceinline__ uint32_t pack2_bf16(float a, float b) {
    uint32_t ua = __builtin_bit_cast(uint32_t, a);
    uint32_t ub = __builtin_bit_cast(uint32_t, b);
    ua += 0x7fffu + ((ua >> 16) & 1u);
    ub += 0x7fffu + ((ub >> 16) & 1u);
    return (ua >> 16) | (ub & 0xffff0000u);
}

// Block layout: blocks [0, 8*c0) -> experts 0..7, chunks of 256 tokens.
// Blocks [8*c0, ...) -> overflow expert 8, chunks of 64 tokens (4x finer:
// expert 8 catches pos>=8, i.e. ~4/12 of uniform tokens — balances work).
__global__ __launch_bounds__(TPB, 1) void ltf_kernel(
    const int* __restrict__ pos, const float* __restrict__ x,
    const float* __restrict__ W, const float* __restrict__ bias,
    float* __restrict__ y, int ntok, int c0)
{
    __shared__ uint32_t Wp[D * (D / 2)];  // 32 KB: W[r] as packed bf16 pairs, [d][e/2]
    __shared__ float XT[4][D * 8];        // 16 KB: per-wave transposed x for 8 tokens
    __shared__ int lst[256];
    __shared__ int cnt;

    const int tid = threadIdx.x;
    const int lane = tid & 63;
    const int wv = tid >> 6;
    const int bid = blockIdx.x;

    int r, start, C;
    if (bid < 8 * c0) { r = bid / c0; start = (bid - r * c0) * 256; C = 256; }
    else              { r = 8; start = (bid - 8 * c0) * 64; C = 64; }

    if (tid == 0) cnt = 0;

    // Stage W[r] -> LDS as bf16 pairs. Wp[d*64 + ep] holds e=2ep, 2ep+1.
    const float2* Wr2 = reinterpret_cast<const float2*>(W + (size_t)r * D * D);
    #pragma unroll
    for (int i = 0; i < (D * D / 2) / TPB; ++i) {
        int idx = i * TPB + tid;
        float2 w = Wr2[idx];
        Wp[idx] = pack2_bf16(w.x, w.y);
    }
    __syncthreads();

    // Ballot-compact this chunk's tokens whose (clamped) expert == r.
    if (wv < (C >> 6)) {
        int t = start + (wv << 6) + lane;
        bool m = false;
        if (t < ntok) {
            int p = pos[t];
            int rp = p < (NEXP - 1) ? p : (NEXP - 1);
            m = (rp == r);
        }
        unsigned long long mask = __ballot(m);
        int pre = __popcll(mask & ((1ull << lane) - 1ull));
        int nm = __popcll(mask);
        int base = 0;
        if (lane == 0 && nm > 0) base = atomicAdd(&cnt, nm);
        base = __shfl(base, 0);
        if (m) lst[base + pre] = t;
    }
    __syncthreads();

    const int nc = cnt;
    float* xt = XT[wv];
    // lane covers e = 2*lane, 2*lane+1
    const float2 bv = reinterpret_cast<const float2*>(bias + (size_t)r * D)[lane];

    for (int g = wv; g * 8 < nc; g += 4) {
        const int gb = g * 8;
        int valid = nc - gb; if (valid > 8) valid = 8;

        // Stage 8 token x-vectors transposed: xt[d*8 + t] = x[tok_t][d].
        // lane -> token ti = lane/8, d-segment seg = lane%8 (16 d's, 4 float4).
        const int ti = lane >> 3, seg = lane & 7;
        int tsel = ti < valid ? ti : valid - 1;  // clamp tail to dummy dup
        int mytok = lst[gb + tsel];
        const float4* xs = reinterpret_cast<const float4*>(x + (size_t)mytok * D + seg * 16);
        #pragma unroll
        for (int j = 0; j < 4; ++j) {
            float4 v = xs[j];
            int d0 = seg * 16 + j * 4;
            xt[(d0 + 0) * 8 + ti] = v.x;
            xt[(d0 + 1) * 8 + ti] = v.y;
            xt[(d0 + 2) * 8 + ti] = v.z;
            xt[(d0 + 3) * 8 + ti] = v.w;
        }

        float acc0[8], acc1[8];
        #pragma unroll
        for (int t = 0; t < 8; ++t) { acc0[t] = 0.f; acc1[t] = 0.f; }

        // Inner loop per d: 1 ds_read_b32 (W pair, conflict-free) +
        // 2 broadcast ds_read_b128 (x for 8 tokens) + 2 unpack + 16 FMA.
        #pragma unroll 4
        for (int d = 0; d < D; ++d) {
            uint32_t w2 = Wp[d * 64 + lane];
            float w0 = __builtin_bit_cast(float, w2 << 16);
            float w1 = __builtin_bit_cast(float, w2 & 0xffff0000u);
            const float4* xr = reinterpret_cast<const float4*>(&xt[d * 8]);
            float4 a = xr[0];
            float4 c = xr[1];
            acc0[0] += w0 * a.x; acc1[0] += w1 * a.x;
            acc0[1] += w0 * a.y; acc1[1] += w1 * a.y;
            acc0[2] += w0 * a.z; acc1[2] += w1 * a.z;
            acc0[3] += w0 * a.w; acc1[3] += w1 * a.w;
            acc0[4] += w0 * c.x; acc1[4] += w1 * c.x;
            acc0[5] += w0 * c.y; acc1[5] += w1 * c.y;
            acc0[6] += w0 * c.z; acc1[6] += w1 * c.z;
            acc0[7] += w0 * c.w; acc1[7] += w1 * c.w;
        }

        #pragma unroll
        for (int t = 0; t < 8; ++t) {
            if (t < valid) {
                int tk = lst[gb + t];
                float2 o;
                o.x = acc0[t] + bv.x;
                o.y = acc1[t] + bv.y;
                reinterpret_cast<float2*>(y + (size_t)tk * D)[lane] = o;
            }
        }
    }
}

extern "C" void kernel_launch(void* const* d_in, const int* in_sizes, int n_in,
                              void* d_out, int out_size, void* d_ws, size_t ws_size,
                              hipStream_t stream) {
    const int* pos  = (const int*)d_in[0];
    const float* x  = (const float*)d_in[1];
    const float* W  = (const float*)d_in[2];
    const float* b  = (const float*)d_in[3];
    float* y = (float*)d_out;

    int ntok = in_sizes[0];               // T*B = 8192
    int c0 = (ntok + 255) / 256;          // chunks per non-overflow expert
    int grid = 8 * c0 + (ntok + 63) / 64; // + fine chunks for overflow expert
    ltf_kernel<<<grid, TPB, 0, stream>>>(pos, x, W, b, y, ntok, c0);
}